// Round 1
// baseline (9698.477 us; speedup 1.0000x reference)
//
#include <hip/hip_runtime.h>
#include <math.h>

#define NND 100000
#define TT 24
#define FI 16
#define HD 128
#define GD 384   // 3*HD
#define OD 64
#define NE 1600000

__device__ __forceinline__ float fsigmoid(float v) { return 1.0f / (1.0f + __expf(-v)); }
__device__ __forceinline__ float ftanh(float v) { return 1.0f - 2.0f / (1.0f + __expf(2.0f * v)); }

// ---------------- transpose W[rows][cols] -> WT[cols][rows] ----------------
__global__ void transpose_kernel(const float* __restrict__ W, float* __restrict__ WT,
                                 int rows, int cols) {
    int idx = blockIdx.x * 256 + threadIdx.x;
    if (idx < rows * cols) {
        int r = idx / cols, c = idx % cols;
        WT[c * rows + r] = W[idx];
    }
}

// ---------------- GRU: 64 nodes per 512-thread block ----------------
// thread tile: 4 nodes (ng = tid&15) x 4 h-indices (jg = tid>>4)
__global__ __launch_bounds__(512, 4) void gru_kernel(
    const float* __restrict__ x,      // [N][T][16]
    const float* __restrict__ WihT,   // [16][384]
    const float* __restrict__ WhhT,   // [128][384]
    const float* __restrict__ bih,    // [384]
    const float* __restrict__ bhh,    // [384]
    float* __restrict__ hout)         // [N][128]
{
    __shared__ float hT[HD][68];   // h transposed: [k][node], pad 68 (16B-aligned rows, low conflicts)
    __shared__ float xT[FI][68];

    const int tid = threadIdx.x;
    const int ng = tid & 15;
    const int jg = tid >> 4;          // 0..31
    const int n0 = ng * 4;
    const int j0 = jg * 4;
    const int gbase = blockIdx.x * 64;

    for (int i = tid; i < HD * 68; i += 512) (&hT[0][0])[i] = 0.0f;

    float br[4], bz[4], bni[4], bnh[4];
#pragma unroll
    for (int jj = 0; jj < 4; ++jj) {
        int j = j0 + jj;
        br[jj]  = bih[j] + bhh[j];
        bz[jj]  = bih[HD + j] + bhh[HD + j];
        bni[jj] = bih[2 * HD + j];
        bnh[jj] = bhh[2 * HD + j];
    }
    __syncthreads();

    for (int t = 0; t < TT; ++t) {
        // stage x[:,t,:] for the 64 nodes, transposed
        if (tid < 256) {
            int n = tid >> 2, f4 = (tid & 3) * 4;
            int gn = gbase + n; if (gn > NND - 1) gn = NND - 1;
            float4 v = *(const float4*)(x + (size_t)gn * (TT * FI) + t * FI + f4);
            xT[f4 + 0][n] = v.x; xT[f4 + 1][n] = v.y;
            xT[f4 + 2][n] = v.z; xT[f4 + 3][n] = v.w;
        }
        __syncthreads();

        float ar[4][4], az[4][4], anh_[4][4], ani[4][4];
#pragma unroll
        for (int a = 0; a < 4; ++a)
#pragma unroll
            for (int b = 0; b < 4; ++b) { ar[a][b] = 0.f; az[a][b] = 0.f; anh_[a][b] = 0.f; ani[a][b] = 0.f; }

        // input-projection part (k over 16 features)
#pragma unroll 4
        for (int f = 0; f < FI; ++f) {
            float4 xv4 = *(const float4*)&xT[f][n0];
            const float* w = WihT + f * GD + j0;
            float4 wr4 = *(const float4*)(w);
            float4 wz4 = *(const float4*)(w + HD);
            float4 wn4 = *(const float4*)(w + 2 * HD);
            float xv[4] = {xv4.x, xv4.y, xv4.z, xv4.w};
            float wr[4] = {wr4.x, wr4.y, wr4.z, wr4.w};
            float wz[4] = {wz4.x, wz4.y, wz4.z, wz4.w};
            float wn[4] = {wn4.x, wn4.y, wn4.z, wn4.w};
#pragma unroll
            for (int jj = 0; jj < 4; ++jj)
#pragma unroll
                for (int nn = 0; nn < 4; ++nn) {
                    ar[jj][nn]  = fmaf(wr[jj], xv[nn], ar[jj][nn]);
                    az[jj][nn]  = fmaf(wz[jj], xv[nn], az[jj][nn]);
                    ani[jj][nn] = fmaf(wn[jj], xv[nn], ani[jj][nn]);
                }
        }

        // hidden-projection part (k over 128)
#pragma unroll 2
        for (int k = 0; k < HD; ++k) {
            float4 hv4 = *(const float4*)&hT[k][n0];
            const float* w = WhhT + k * GD + j0;
            float4 wr4 = *(const float4*)(w);
            float4 wz4 = *(const float4*)(w + HD);
            float4 wn4 = *(const float4*)(w + 2 * HD);
            float hv[4] = {hv4.x, hv4.y, hv4.z, hv4.w};
            float wr[4] = {wr4.x, wr4.y, wr4.z, wr4.w};
            float wz[4] = {wz4.x, wz4.y, wz4.z, wz4.w};
            float wn[4] = {wn4.x, wn4.y, wn4.z, wn4.w};
#pragma unroll
            for (int jj = 0; jj < 4; ++jj)
#pragma unroll
                for (int nn = 0; nn < 4; ++nn) {
                    ar[jj][nn]   = fmaf(wr[jj], hv[nn], ar[jj][nn]);
                    az[jj][nn]   = fmaf(wz[jj], hv[nn], az[jj][nn]);
                    anh_[jj][nn] = fmaf(wn[jj], hv[nn], anh_[jj][nn]);
                }
        }
        __syncthreads();   // all hT reads done before updates

        float hnew[4][4];
#pragma unroll
        for (int jj = 0; jj < 4; ++jj) {
            float4 ho4 = *(const float4*)&hT[j0 + jj][n0];
            float ho[4] = {ho4.x, ho4.y, ho4.z, ho4.w};
#pragma unroll
            for (int nn = 0; nn < 4; ++nn) {
                float r  = fsigmoid(ar[jj][nn] + br[jj]);
                float z  = fsigmoid(az[jj][nn] + bz[jj]);
                float nv = ftanh(ani[jj][nn] + bni[jj] + r * (anh_[jj][nn] + bnh[jj]));
                hnew[jj][nn] = nv + z * (ho[nn] - nv);
            }
            *(float4*)&hT[j0 + jj][n0] =
                make_float4(hnew[jj][0], hnew[jj][1], hnew[jj][2], hnew[jj][3]);
        }

        if (t == TT - 1) {
#pragma unroll
            for (int nn = 0; nn < 4; ++nn) {
                int gn = gbase + n0 + nn;
                if (gn < NND)
                    *(float4*)(hout + (size_t)gn * HD + j0) =
                        make_float4(hnew[0][nn], hnew[1][nn], hnew[2][nn], hnew[3][nn]);
            }
        }
        // next iteration's staging barrier orders hT writes vs next reads
    }
}

// ---------------- projection: Y[N][M] = X[N][128] @ WT (+bias) (+X residual) ----------------
template <int M, bool BIAS, bool RES>
__global__ __launch_bounds__(256) void proj_kernel(
    const float* __restrict__ X,    // [N][128]
    const float* __restrict__ WT,   // [128][M] (k-major)
    const float* __restrict__ bias, // [M] or nullptr
    float* __restrict__ Y,          // [N][M]
    int n_total)
{
    constexpr int K = 128;
    constexpr int MG = M / 4;
    constexpr int NG = 256 / MG;
    constexpr int NN = 64 / NG;
    __shared__ float XT[K][68];

    const int tid = threadIdx.x;
    const int gbase = blockIdx.x * 64;

#pragma unroll
    for (int i = 0; i < 8; ++i) {
        int lin = tid + 256 * i;     // 0..2047
        int n = lin >> 5;            // 0..63
        int k4 = (lin & 31) * 4;
        int gn = gbase + n; if (gn >= n_total) gn = n_total - 1;
        float4 v = *(const float4*)(X + (size_t)gn * K + k4);
        XT[k4 + 0][n] = v.x; XT[k4 + 1][n] = v.y;
        XT[k4 + 2][n] = v.z; XT[k4 + 3][n] = v.w;
    }
    __syncthreads();

    const int mg = tid % MG, ng = tid / MG;
    const int m0 = mg * 4, nb = ng * NN;
    float acc[NN][4];
#pragma unroll
    for (int a = 0; a < NN; ++a)
#pragma unroll
        for (int b = 0; b < 4; ++b) acc[a][b] = 0.f;

    for (int k = 0; k < K; ++k) {
        float4 wv4 = *(const float4*)(WT + k * M + m0);
        float wv[4] = {wv4.x, wv4.y, wv4.z, wv4.w};
        float xv[NN];
#pragma unroll
        for (int c = 0; c < NN; c += 4) {
            float4 xt = *(const float4*)&XT[k][nb + c];
            xv[c + 0] = xt.x; xv[c + 1] = xt.y; xv[c + 2] = xt.z; xv[c + 3] = xt.w;
        }
#pragma unroll
        for (int ni = 0; ni < NN; ++ni)
#pragma unroll
            for (int mm = 0; mm < 4; ++mm)
                acc[ni][mm] = fmaf(xv[ni], wv[mm], acc[ni][mm]);
    }

    float bv[4] = {0.f, 0.f, 0.f, 0.f};
    if (BIAS) { float4 b4 = *(const float4*)(bias + m0); bv[0]=b4.x; bv[1]=b4.y; bv[2]=b4.z; bv[3]=b4.w; }
#pragma unroll
    for (int ni = 0; ni < NN; ++ni) {
        int gn = gbase + nb + ni;
        if (gn < n_total) {
            float r0 = acc[ni][0] + bv[0], r1 = acc[ni][1] + bv[1];
            float r2 = acc[ni][2] + bv[2], r3 = acc[ni][3] + bv[3];
            if constexpr (RES) {
                float4 xr = *(const float4*)(X + (size_t)gn * K + m0);
                r0 += xr.x; r1 += xr.y; r2 += xr.z; r3 += xr.w;
            }
            *(float4*)(Y + (size_t)gn * M + m0) = make_float4(r0, r1, r2, r3);
        }
    }
}

// ---------------- edge aggregation ----------------
__global__ void count_kernel(const int* __restrict__ dst, int* __restrict__ cnt) {
    int e = blockIdx.x * 256 + threadIdx.x;
    if (e < NE) atomicAdd(&cnt[dst[e]], 1);
}
__global__ void inv_kernel(const int* __restrict__ cnt, float* __restrict__ invc) {
    int i = blockIdx.x * 256 + threadIdx.x;
    if (i < NND) { int c = cnt[i]; invc[i] = 1.0f / (float)(c > 0 ? c : 1); }
}

template <int F>
__global__ void scatter_kernel(const float* __restrict__ P,
                               const int* __restrict__ src, const int* __restrict__ dst,
                               float* __restrict__ agg) {
    constexpr int F4 = F / 4;
    unsigned gid = blockIdx.x * 256u + threadIdx.x;
    unsigned e = gid / F4;
    int f = (int)(gid % F4) * 4;
    if (e >= NE) return;
    int s = src[e], d = dst[e];
    float4 v = *(const float4*)(P + (size_t)s * F + f);
    float* a = agg + (size_t)d * F + f;
    atomicAdd(a + 0, v.x); atomicAdd(a + 1, v.y);
    atomicAdd(a + 2, v.z); atomicAdd(a + 3, v.w);
}

template <int F, bool RELU>
__global__ void combine_kernel(const float* __restrict__ agg, const float* __restrict__ invc,
                               const float* __restrict__ q, float* __restrict__ outp) {
    constexpr int F4 = F / 4;
    unsigned gid = blockIdx.x * 256u + threadIdx.x;
    if (gid >= (unsigned)NND * F4) return;
    int n = gid / F4;
    int f = (int)(gid % F4) * 4;
    float iv = invc[n];
    float4 av = *(const float4*)(agg + (size_t)n * F + f);
    float4 qv = *(const float4*)(q + (size_t)n * F + f);
    float r0 = av.x * iv + qv.x, r1 = av.y * iv + qv.y;
    float r2 = av.z * iv + qv.z, r3 = av.w * iv + qv.w;
    if (RELU) { r0 = fmaxf(r0, 0.f); r1 = fmaxf(r1, 0.f); r2 = fmaxf(r2, 0.f); r3 = fmaxf(r3, 0.f); }
    *(float4*)(outp + (size_t)n * F + f) = make_float4(r0, r1, r2, r3);
}

// ---------------- launch ----------------
extern "C" void kernel_launch(void* const* d_in, const int* in_sizes, int n_in,
                              void* d_out, int out_size, void* d_ws, size_t ws_size,
                              hipStream_t stream) {
    const float* x   = (const float*)d_in[0];
    const int*   edg = (const int*)d_in[1];
    const int*   src = edg;
    const int*   dst = edg + NE;
    const float* Wih = (const float*)d_in[2];
    const float* Whh = (const float*)d_in[3];
    const float* bih = (const float*)d_in[4];
    const float* bhh = (const float*)d_in[5];
    const float* W1l = (const float*)d_in[6];
    const float* b1  = (const float*)d_in[7];
    const float* W1r = (const float*)d_in[8];
    const float* W2l = (const float*)d_in[9];
    const float* b2  = (const float*)d_in[10];
    const float* W2r = (const float*)d_in[11];
    float* out = (float*)d_out;

    char* wsp = (char*)d_ws;
    auto alloc = [&](size_t nbytes) {
        char* p = wsp; wsp += (nbytes + 255) & ~(size_t)255; return p;
    };
    float* WihT = (float*)alloc((size_t)FI * GD * 4);
    float* WhhT = (float*)alloc((size_t)HD * GD * 4);
    float* WT1l = (float*)alloc((size_t)HD * HD * 4);
    float* WT1r = (float*)alloc((size_t)HD * HD * 4);
    float* WT2l = (float*)alloc((size_t)HD * OD * 4);
    float* WT2r = (float*)alloc((size_t)HD * OD * 4);
    int*   cnt  = (int*)alloc((size_t)NND * 4);
    float* invc = (float*)alloc((size_t)NND * 4);
    float* h    = (float*)alloc((size_t)NND * HD * 4);
    float* p    = (float*)alloc((size_t)NND * HD * 4);
    float* q    = (float*)alloc((size_t)NND * HD * 4);
    float* agg  = (float*)alloc((size_t)NND * HD * 4);

    // zero accumulators (every call: harness replays the graph without re-poisoning)
    hipMemsetAsync(agg, 0, (size_t)NND * HD * 4, stream);
    hipMemsetAsync(cnt, 0, (size_t)NND * 4, stream);

    // weight transposes (k-major for coalesced inner loops)
    transpose_kernel<<<(GD * FI + 255) / 256, 256, 0, stream>>>(Wih, WihT, GD, FI);
    transpose_kernel<<<(GD * HD + 255) / 256, 256, 0, stream>>>(Whh, WhhT, GD, HD);
    transpose_kernel<<<(HD * HD + 255) / 256, 256, 0, stream>>>(W1l, WT1l, HD, HD);
    transpose_kernel<<<(HD * HD + 255) / 256, 256, 0, stream>>>(W1r, WT1r, HD, HD);
    transpose_kernel<<<(OD * HD + 255) / 256, 256, 0, stream>>>(W2l, WT2l, OD, HD);
    transpose_kernel<<<(OD * HD + 255) / 256, 256, 0, stream>>>(W2r, WT2r, OD, HD);

    // GRU -> h [N,128]
    const int nblk = (NND + 63) / 64;
    gru_kernel<<<nblk, 512, 0, stream>>>(x, WihT, WhhT, bih, bhh, h);

    // layer 1: project first, then mean-aggregate
    proj_kernel<HD, false, false><<<nblk, 256, 0, stream>>>(h, WT1l, nullptr, p, NND);
    proj_kernel<HD, true,  true ><<<nblk, 256, 0, stream>>>(h, WT1r, b1, q, NND);  // q = h@W1r^T + b1 + h

    count_kernel<<<(NE + 255) / 256, 256, 0, stream>>>(dst, cnt);
    inv_kernel<<<(NND + 255) / 256, 256, 0, stream>>>(cnt, invc);

    scatter_kernel<HD><<<(NE * (HD / 4) + 255) / 256, 256, 0, stream>>>(p, src, dst, agg);
    combine_kernel<HD, true><<<(NND * (HD / 4) + 255) / 256, 256, 0, stream>>>(agg, invc, q, h); // g -> h buf

    // layer 2 (project to 64 first -> halves scatter traffic)
    hipMemsetAsync(agg, 0, (size_t)NND * OD * 4, stream);
    proj_kernel<OD, false, false><<<nblk, 256, 0, stream>>>(h, WT2l, nullptr, p, NND);
    proj_kernel<OD, true,  false><<<nblk, 256, 0, stream>>>(h, WT2r, b2, q, NND);

    scatter_kernel<OD><<<(NE * (OD / 4) + 255) / 256, 256, 0, stream>>>(p, src, dst, agg);
    combine_kernel<OD, false><<<(NND * (OD / 4) + 255) / 256, 256, 0, stream>>>(agg, invc, q, out);
}

// Round 2
// 5108.531 us; speedup vs baseline: 1.8985x; 1.8985x over previous
//
#include <hip/hip_runtime.h>
#include <math.h>

#define NND 100000
#define TT 24
#define FI 16
#define HD 128
#define GD 384   // 3*HD
#define OD 64
#define NE 1600000

typedef __bf16 bf16x8 __attribute__((ext_vector_type(8)));
typedef float f32x4 __attribute__((ext_vector_type(4)));
typedef unsigned short u16;
typedef unsigned int u32;

__device__ __forceinline__ float fsigmoid(float v) {
    return __builtin_amdgcn_rcpf(1.0f + __expf(-v));
}
__device__ __forceinline__ float ftanh(float v) {
    return 1.0f - 2.0f * __builtin_amdgcn_rcpf(1.0f + __expf(2.0f * v));
}
__device__ __forceinline__ u16 f2b(float f) {
    u32 u = __float_as_uint(f);
    u32 r = (u + 0x7FFFu + ((u >> 16) & 1u)) >> 16;
    return (u16)r;
}

union BF8U { u16 s[8]; bf16x8 v; };

// ---------------- transpose W[rows][cols] -> WT[cols][rows] ----------------
__global__ void transpose_kernel(const float* __restrict__ W, float* __restrict__ WT,
                                 int rows, int cols) {
    int idx = blockIdx.x * 256 + threadIdx.x;
    if (idx < rows * cols) {
        int r = idx / cols, c = idx % cols;
        WT[c * rows + r] = W[idx];
    }
}

// ---------------- pack GRU weights into MFMA A-fragments (bf16) ----------------
// Ah frag (gt 0..23, s 0..3): lane holds row = gt*16+(lane&15), k = s*32+(lane>>4)*8 .. +8  of Whh[384][128]
// Ai frag (gt 0..23):         lane holds row = gt*16+(lane&15), k = (lane>>4)*8 .. +8 (<16) of Wih[384][16], else 0
__global__ void pack_w_kernel(const float* __restrict__ Whh, const float* __restrict__ Wih,
                              u16* __restrict__ Ap, u16* __restrict__ Aip) {
    int id = blockIdx.x * 256 + threadIdx.x;
    if (id < 6144) {
        int lane = id & 63, fs = id >> 6;
        int s = fs & 3, gt = fs >> 2;
        int row = gt * 16 + (lane & 15);
        int k0 = s * 32 + (lane >> 4) * 8;
        const float* src = Whh + (size_t)row * HD + k0;
        u16 o[8];
#pragma unroll
        for (int e = 0; e < 8; ++e) o[e] = f2b(src[e]);
        u32* dst = (u32*)(Ap + (size_t)id * 8);
#pragma unroll
        for (int e = 0; e < 4; ++e) dst[e] = (u32)o[2 * e] | ((u32)o[2 * e + 1] << 16);
    } else if (id < 7680) {
        int id2 = id - 6144;
        int lane = id2 & 63, gt = id2 >> 6;
        int row = gt * 16 + (lane & 15);
        int k0 = (lane >> 4) * 8;
        u16 o[8] = {0, 0, 0, 0, 0, 0, 0, 0};
        if (k0 < FI) {
            const float* src = Wih + (size_t)row * FI + k0;
#pragma unroll
            for (int e = 0; e < 8; ++e) o[e] = f2b(src[e]);
        }
        u32* dst = (u32*)(Aip + (size_t)id2 * 8);
#pragma unroll
        for (int e = 0; e < 4; ++e) dst[e] = (u32)o[2 * e] | ((u32)o[2 * e + 1] << 16);
    }
}

// ---------------- GRU via MFMA: 64 nodes / 512-thread block ----------------
// D[gate][node] = Whh x h  (+ Wih x x_t). Wave w owns gate tiles {w, w+8, w+16}
// -> lane holds r/z/ghn/gin for j = 16w + (lane>>4)*4 + reg, node = m*16 + (lane&15).
__global__ __launch_bounds__(512) void gru_mfma_kernel(
    const float* __restrict__ x,      // [N][T][16]
    const u16* __restrict__ Ap,       // [24][4][64][8] bf16 (Whh frags)
    const u16* __restrict__ Aip,      // [24][64][8] bf16 (Wih frags)
    const float* __restrict__ bih, const float* __restrict__ bhh,
    float* __restrict__ hout)         // [N][128] f32
{
    __shared__ u16 hb[64][136];       // h bf16, pad 136 (row 272B, ~2-way banks)

    const int tid = threadIdx.x;
    const int w = tid >> 6, lane = tid & 63;
    const int l15 = lane & 15, g = lane >> 4;
    const int gbase = blockIdx.x * 64;
    const int j0 = w * 16 + g * 4;

    // zero h LDS
    for (int i = tid; i < 64 * 136 / 2; i += 512) ((u32*)hb)[i] = 0u;

    // persistent weight fragments
    bf16x8 Ah[3][4], Ai[3];
#pragma unroll
    for (int a = 0; a < 3; ++a) {
        int gt = w + a * 8;
#pragma unroll
        for (int s = 0; s < 4; ++s)
            Ah[a][s] = *(const bf16x8*)(Ap + ((size_t)(gt * 4 + s) * 64 + lane) * 8);
        Ai[a] = *(const bf16x8*)(Aip + ((size_t)gt * 64 + lane) * 8);
    }

    // biases for this lane's j range
    f32x4 br4, bz4, bnh4, bni4;
    {
        f32x4 a0 = *(const f32x4*)(bih + j0),        b0 = *(const f32x4*)(bhh + j0);
        f32x4 a1 = *(const f32x4*)(bih + 128 + j0),  b1 = *(const f32x4*)(bhh + 128 + j0);
        br4 = a0 + b0; bz4 = a1 + b1;
        bnh4 = *(const f32x4*)(bhh + 256 + j0);
        bni4 = *(const f32x4*)(bih + 256 + j0);
    }

    f32x4 hreg[4];
#pragma unroll
    for (int m = 0; m < 4; ++m) hreg[m] = (f32x4){0.f, 0.f, 0.f, 0.f};

    int nodeg[4];
#pragma unroll
    for (int m = 0; m < 4; ++m) {
        int nd = gbase + m * 16 + l15;
        nodeg[m] = nd < NND ? nd : NND - 1;
    }

    __syncthreads();

    for (int t = 0; t < TT; ++t) {
        // x B-fragments (B[k][node] = x[node][k]); k>=16 lanes hold zero
        bf16x8 xf[4];
#pragma unroll
        for (int m = 0; m < 4; ++m) {
            BF8U u;
            if (g < 2) {
                const float* xp = x + ((size_t)nodeg[m] * TT + t) * FI + g * 8;
                float4 v0 = *(const float4*)xp;
                float4 v1 = *(const float4*)(xp + 4);
                u.s[0] = f2b(v0.x); u.s[1] = f2b(v0.y); u.s[2] = f2b(v0.z); u.s[3] = f2b(v0.w);
                u.s[4] = f2b(v1.x); u.s[5] = f2b(v1.y); u.s[6] = f2b(v1.z); u.s[7] = f2b(v1.w);
            } else {
#pragma unroll
                for (int e = 0; e < 8; ++e) u.s[e] = 0;
            }
            xf[m] = u.v;
        }

        f32x4 acc[3][4], acci[4];
#pragma unroll
        for (int a = 0; a < 3; ++a)
#pragma unroll
            for (int m = 0; m < 4; ++m) acc[a][m] = (f32x4){0.f, 0.f, 0.f, 0.f};
#pragma unroll
        for (int m = 0; m < 4; ++m) acci[m] = (f32x4){0.f, 0.f, 0.f, 0.f};

        // G_h: K=128 in 4 k-steps
#pragma unroll
        for (int s = 0; s < 4; ++s) {
            bf16x8 bf[4];
#pragma unroll
            for (int m = 0; m < 4; ++m)
                bf[m] = *(const bf16x8*)&hb[m * 16 + l15][s * 32 + g * 8];
#pragma unroll
            for (int a = 0; a < 3; ++a)
#pragma unroll
                for (int m = 0; m < 4; ++m)
                    acc[a][m] = __builtin_amdgcn_mfma_f32_16x16x32_bf16(Ah[a][s], bf[m], acc[a][m], 0, 0, 0);
        }
        // G_i: r,z fused into acc; n-part separate
#pragma unroll
        for (int m = 0; m < 4; ++m) {
            acc[0][m] = __builtin_amdgcn_mfma_f32_16x16x32_bf16(Ai[0], xf[m], acc[0][m], 0, 0, 0);
            acc[1][m] = __builtin_amdgcn_mfma_f32_16x16x32_bf16(Ai[1], xf[m], acc[1][m], 0, 0, 0);
            acci[m]   = __builtin_amdgcn_mfma_f32_16x16x32_bf16(Ai[2], xf[m], acci[m], 0, 0, 0);
        }
        __syncthreads();   // B1: all hb reads complete

        // register-local gates + h update; write h bf16 for next step
#pragma unroll
        for (int m = 0; m < 4; ++m) {
            u16 hp[4];
#pragma unroll
            for (int r = 0; r < 4; ++r) {
                float rr = fsigmoid(acc[0][m][r] + br4[r]);
                float zz = fsigmoid(acc[1][m][r] + bz4[r]);
                float nn = ftanh(acci[m][r] + bni4[r] + rr * (acc[2][m][r] + bnh4[r]));
                float h = nn + zz * (hreg[m][r] - nn);
                hreg[m][r] = h;
                hp[r] = f2b(h);
            }
            u32 lo = (u32)hp[0] | ((u32)hp[1] << 16);
            u32 hi = (u32)hp[2] | ((u32)hp[3] << 16);
            *(uint2*)&hb[m * 16 + l15][j0] = make_uint2(lo, hi);
        }
        __syncthreads();   // B2: hb ready for next step
    }

    // final hidden state (f32 from registers)
#pragma unroll
    for (int m = 0; m < 4; ++m) {
        int nd = gbase + m * 16 + l15;
        if (nd < NND)
            *(f32x4*)(hout + (size_t)nd * HD + j0) = hreg[m];
    }
}

// ---------------- projection: Y[N][M] = X[N][128] @ WT (+bias) (+X residual) ----------------
template <int M, bool BIAS, bool RES>
__global__ __launch_bounds__(256) void proj_kernel(
    const float* __restrict__ X,    // [N][128]
    const float* __restrict__ WT,   // [128][M] (k-major)
    const float* __restrict__ bias, // [M] or nullptr
    float* __restrict__ Y,          // [N][M]
    int n_total)
{
    constexpr int K = 128;
    constexpr int MG = M / 4;
    constexpr int NG = 256 / MG;
    constexpr int NN = 64 / NG;
    __shared__ float XT[K][68];

    const int tid = threadIdx.x;
    const int gbase = blockIdx.x * 64;

#pragma unroll
    for (int i = 0; i < 8; ++i) {
        int lin = tid + 256 * i;
        int n = lin >> 5;
        int k4 = (lin & 31) * 4;
        int gn = gbase + n; if (gn >= n_total) gn = n_total - 1;
        float4 v = *(const float4*)(X + (size_t)gn * K + k4);
        XT[k4 + 0][n] = v.x; XT[k4 + 1][n] = v.y;
        XT[k4 + 2][n] = v.z; XT[k4 + 3][n] = v.w;
    }
    __syncthreads();

    const int mg = tid % MG, ng = tid / MG;
    const int m0 = mg * 4, nb = ng * NN;
    float acc[NN][4];
#pragma unroll
    for (int a = 0; a < NN; ++a)
#pragma unroll
        for (int b = 0; b < 4; ++b) acc[a][b] = 0.f;

    for (int k = 0; k < K; ++k) {
        float4 wv4 = *(const float4*)(WT + k * M + m0);
        float wv[4] = {wv4.x, wv4.y, wv4.z, wv4.w};
        float xv[NN];
#pragma unroll
        for (int c = 0; c < NN; c += 4) {
            float4 xt = *(const float4*)&XT[k][nb + c];
            xv[c + 0] = xt.x; xv[c + 1] = xt.y; xv[c + 2] = xt.z; xv[c + 3] = xt.w;
        }
#pragma unroll
        for (int ni = 0; ni < NN; ++ni)
#pragma unroll
            for (int mm = 0; mm < 4; ++mm)
                acc[ni][mm] = fmaf(xv[ni], wv[mm], acc[ni][mm]);
    }

    float bv[4] = {0.f, 0.f, 0.f, 0.f};
    if (BIAS) { float4 b4 = *(const float4*)(bias + m0); bv[0]=b4.x; bv[1]=b4.y; bv[2]=b4.z; bv[3]=b4.w; }
#pragma unroll
    for (int ni = 0; ni < NN; ++ni) {
        int gn = gbase + nb + ni;
        if (gn < n_total) {
            float r0 = acc[ni][0] + bv[0], r1 = acc[ni][1] + bv[1];
            float r2 = acc[ni][2] + bv[2], r3 = acc[ni][3] + bv[3];
            if constexpr (RES) {
                float4 xr = *(const float4*)(X + (size_t)gn * K + m0);
                r0 += xr.x; r1 += xr.y; r2 += xr.z; r3 += xr.w;
            }
            *(float4*)(Y + (size_t)gn * M + m0) = make_float4(r0, r1, r2, r3);
        }
    }
}

// ---------------- edge aggregation ----------------
__global__ void count_kernel(const int* __restrict__ dst, int* __restrict__ cnt) {
    int e = blockIdx.x * 256 + threadIdx.x;
    if (e < NE) atomicAdd(&cnt[dst[e]], 1);
}
__global__ void inv_kernel(const int* __restrict__ cnt, float* __restrict__ invc) {
    int i = blockIdx.x * 256 + threadIdx.x;
    if (i < NND) { int c = cnt[i]; invc[i] = 1.0f / (float)(c > 0 ? c : 1); }
}

template <int F>
__global__ void scatter_kernel(const float* __restrict__ P,
                               const int* __restrict__ src, const int* __restrict__ dst,
                               float* __restrict__ agg) {
    constexpr int F4 = F / 4;
    unsigned gid = blockIdx.x * 256u + threadIdx.x;
    unsigned e = gid / F4;
    int f = (int)(gid % F4) * 4;
    if (e >= NE) return;
    int s = src[e], d = dst[e];
    float4 v = *(const float4*)(P + (size_t)s * F + f);
    float* a = agg + (size_t)d * F + f;
    atomicAdd(a + 0, v.x); atomicAdd(a + 1, v.y);
    atomicAdd(a + 2, v.z); atomicAdd(a + 3, v.w);
}

template <int F, bool RELU>
__global__ void combine_kernel(const float* __restrict__ agg, const float* __restrict__ invc,
                               const float* __restrict__ q, float* __restrict__ outp) {
    constexpr int F4 = F / 4;
    unsigned gid = blockIdx.x * 256u + threadIdx.x;
    if (gid >= (unsigned)NND * F4) return;
    int n = gid / F4;
    int f = (int)(gid % F4) * 4;
    float iv = invc[n];
    float4 av = *(const float4*)(agg + (size_t)n * F + f);
    float4 qv = *(const float4*)(q + (size_t)n * F + f);
    float r0 = av.x * iv + qv.x, r1 = av.y * iv + qv.y;
    float r2 = av.z * iv + qv.z, r3 = av.w * iv + qv.w;
    if (RELU) { r0 = fmaxf(r0, 0.f); r1 = fmaxf(r1, 0.f); r2 = fmaxf(r2, 0.f); r3 = fmaxf(r3, 0.f); }
    *(float4*)(outp + (size_t)n * F + f) = make_float4(r0, r1, r2, r3);
}

// ---------------- launch ----------------
extern "C" void kernel_launch(void* const* d_in, const int* in_sizes, int n_in,
                              void* d_out, int out_size, void* d_ws, size_t ws_size,
                              hipStream_t stream) {
    const float* x   = (const float*)d_in[0];
    const int*   edg = (const int*)d_in[1];
    const int*   src = edg;
    const int*   dst = edg + NE;
    const float* Wih = (const float*)d_in[2];
    const float* Whh = (const float*)d_in[3];
    const float* bih = (const float*)d_in[4];
    const float* bhh = (const float*)d_in[5];
    const float* W1l = (const float*)d_in[6];
    const float* b1  = (const float*)d_in[7];
    const float* W1r = (const float*)d_in[8];
    const float* W2l = (const float*)d_in[9];
    const float* b2  = (const float*)d_in[10];
    const float* W2r = (const float*)d_in[11];
    float* out = (float*)d_out;

    char* wsp = (char*)d_ws;
    auto alloc = [&](size_t nbytes) {
        char* p = wsp; wsp += (nbytes + 255) & ~(size_t)255; return p;
    };
    u16*   Ap   = (u16*)alloc((size_t)6144 * 8 * 2);
    u16*   Aip  = (u16*)alloc((size_t)1536 * 8 * 2);
    float* WT1l = (float*)alloc((size_t)HD * HD * 4);
    float* WT1r = (float*)alloc((size_t)HD * HD * 4);
    float* WT2l = (float*)alloc((size_t)HD * OD * 4);
    float* WT2r = (float*)alloc((size_t)HD * OD * 4);
    int*   cnt  = (int*)alloc((size_t)NND * 4);
    float* invc = (float*)alloc((size_t)NND * 4);
    float* h    = (float*)alloc((size_t)NND * HD * 4);
    float* p    = (float*)alloc((size_t)NND * HD * 4);
    float* q    = (float*)alloc((size_t)NND * HD * 4);
    float* agg  = (float*)alloc((size_t)NND * HD * 4);

    hipMemsetAsync(agg, 0, (size_t)NND * HD * 4, stream);
    hipMemsetAsync(cnt, 0, (size_t)NND * 4, stream);

    // prep: GRU weight fragments + proj weight transposes
    pack_w_kernel<<<30, 256, 0, stream>>>(Whh, Wih, Ap, Aip);
    transpose_kernel<<<(HD * HD + 255) / 256, 256, 0, stream>>>(W1l, WT1l, HD, HD);
    transpose_kernel<<<(HD * HD + 255) / 256, 256, 0, stream>>>(W1r, WT1r, HD, HD);
    transpose_kernel<<<(OD * HD + 255) / 256, 256, 0, stream>>>(W2l, WT2l, OD, HD);
    transpose_kernel<<<(OD * HD + 255) / 256, 256, 0, stream>>>(W2r, WT2r, OD, HD);

    // GRU -> h [N,128]
    const int nblk = (NND + 63) / 64;
    gru_mfma_kernel<<<nblk, 512, 0, stream>>>(x, Ap, Aip, bih, bhh, h);

    // layer 1: project first, then mean-aggregate
    proj_kernel<HD, false, false><<<nblk, 256, 0, stream>>>(h, WT1l, nullptr, p, NND);
    proj_kernel<HD, true,  true ><<<nblk, 256, 0, stream>>>(h, WT1r, b1, q, NND);  // q = h@W1r^T + b1 + h

    count_kernel<<<(NE + 255) / 256, 256, 0, stream>>>(dst, cnt);
    inv_kernel<<<(NND + 255) / 256, 256, 0, stream>>>(cnt, invc);

    scatter_kernel<HD><<<(NE * (HD / 4) + 255) / 256, 256, 0, stream>>>(p, src, dst, agg);
    combine_kernel<HD, true><<<(NND * (HD / 4) + 255) / 256, 256, 0, stream>>>(agg, invc, q, h);

    // layer 2 (project to 64 first -> halves scatter traffic)
    hipMemsetAsync(agg, 0, (size_t)NND * OD * 4, stream);
    proj_kernel<OD, false, false><<<nblk, 256, 0, stream>>>(h, WT2l, nullptr, p, NND);
    proj_kernel<OD, true,  false><<<nblk, 256, 0, stream>>>(h, WT2r, b2, q, NND);

    scatter_kernel<OD><<<(NE * (OD / 4) + 255) / 256, 256, 0, stream>>>(p, src, dst, agg);
    combine_kernel<OD, false><<<(NND * (OD / 4) + 255) / 256, 256, 0, stream>>>(agg, invc, q, out);
}

// Round 3
// 1289.550 us; speedup vs baseline: 7.5208x; 3.9615x over previous
//
#include <hip/hip_runtime.h>
#include <math.h>

#define NND 100000
#define TT 24
#define FI 16
#define HD 128
#define GD 384   // 3*HD
#define OD 64
#define NE 1600000

typedef __bf16 bf16x8 __attribute__((ext_vector_type(8)));
typedef float f32x4 __attribute__((ext_vector_type(4)));
typedef unsigned short u16;
typedef unsigned int u32;

__device__ __forceinline__ float fsigmoid(float v) {
    return __builtin_amdgcn_rcpf(1.0f + __expf(-v));
}
__device__ __forceinline__ float ftanh(float v) {
    return 1.0f - 2.0f * __builtin_amdgcn_rcpf(1.0f + __expf(2.0f * v));
}
__device__ __forceinline__ u16 f2b(float f) {
    u32 u = __float_as_uint(f);
    u32 r = (u + 0x7FFFu + ((u >> 16) & 1u)) >> 16;
    return (u16)r;
}

union BF8U { u16 s[8]; bf16x8 v; };

// ---------------- transpose W[rows][cols] -> WT[cols][rows] ----------------
__global__ void transpose_kernel(const float* __restrict__ W, float* __restrict__ WT,
                                 int rows, int cols) {
    int idx = blockIdx.x * 256 + threadIdx.x;
    if (idx < rows * cols) {
        int r = idx / cols, c = idx % cols;
        WT[c * rows + r] = W[idx];
    }
}

// ---------------- pack GRU weights into MFMA A-fragments (bf16) ----------------
__global__ void pack_w_kernel(const float* __restrict__ Whh, const float* __restrict__ Wih,
                              u16* __restrict__ Ap, u16* __restrict__ Aip) {
    int id = blockIdx.x * 256 + threadIdx.x;
    if (id < 6144) {
        int lane = id & 63, fs = id >> 6;
        int s = fs & 3, gt = fs >> 2;
        int row = gt * 16 + (lane & 15);
        int k0 = s * 32 + (lane >> 4) * 8;
        const float* src = Whh + (size_t)row * HD + k0;
        u16 o[8];
#pragma unroll
        for (int e = 0; e < 8; ++e) o[e] = f2b(src[e]);
        u32* dst = (u32*)(Ap + (size_t)id * 8);
#pragma unroll
        for (int e = 0; e < 4; ++e) dst[e] = (u32)o[2 * e] | ((u32)o[2 * e + 1] << 16);
    } else if (id < 7680) {
        int id2 = id - 6144;
        int lane = id2 & 63, gt = id2 >> 6;
        int row = gt * 16 + (lane & 15);
        int k0 = (lane >> 4) * 8;
        u16 o[8] = {0, 0, 0, 0, 0, 0, 0, 0};
        if (k0 < FI) {
            const float* src = Wih + (size_t)row * FI + k0;
#pragma unroll
            for (int e = 0; e < 8; ++e) o[e] = f2b(src[e]);
        }
        u32* dst = (u32*)(Aip + (size_t)id2 * 8);
#pragma unroll
        for (int e = 0; e < 4; ++e) dst[e] = (u32)o[2 * e] | ((u32)o[2 * e + 1] << 16);
    }
}

// ---------------- GRU via MFMA: 64 nodes / 512-thread block ----------------
__global__ __launch_bounds__(512) void gru_mfma_kernel(
    const float* __restrict__ x,      // [N][T][16]
    const u16* __restrict__ Ap,       // [24][4][64][8] bf16 (Whh frags)
    const u16* __restrict__ Aip,      // [24][64][8] bf16 (Wih frags)
    const float* __restrict__ bih, const float* __restrict__ bhh,
    float* __restrict__ hout)         // [N][128] f32
{
    __shared__ u16 hb[64][136];

    const int tid = threadIdx.x;
    const int w = tid >> 6, lane = tid & 63;
    const int l15 = lane & 15, g = lane >> 4;
    const int gbase = blockIdx.x * 64;
    const int j0 = w * 16 + g * 4;

    for (int i = tid; i < 64 * 136 / 2; i += 512) ((u32*)hb)[i] = 0u;

    bf16x8 Ah[3][4], Ai[3];
#pragma unroll
    for (int a = 0; a < 3; ++a) {
        int gt = w + a * 8;
#pragma unroll
        for (int s = 0; s < 4; ++s)
            Ah[a][s] = *(const bf16x8*)(Ap + ((size_t)(gt * 4 + s) * 64 + lane) * 8);
        Ai[a] = *(const bf16x8*)(Aip + ((size_t)gt * 64 + lane) * 8);
    }

    f32x4 br4, bz4, bnh4, bni4;
    {
        f32x4 a0 = *(const f32x4*)(bih + j0),        b0 = *(const f32x4*)(bhh + j0);
        f32x4 a1 = *(const f32x4*)(bih + 128 + j0),  b1 = *(const f32x4*)(bhh + 128 + j0);
        br4 = a0 + b0; bz4 = a1 + b1;
        bnh4 = *(const f32x4*)(bhh + 256 + j0);
        bni4 = *(const f32x4*)(bih + 256 + j0);
    }

    f32x4 hreg[4];
#pragma unroll
    for (int m = 0; m < 4; ++m) hreg[m] = (f32x4){0.f, 0.f, 0.f, 0.f};

    int nodeg[4];
#pragma unroll
    for (int m = 0; m < 4; ++m) {
        int nd = gbase + m * 16 + l15;
        nodeg[m] = nd < NND ? nd : NND - 1;
    }

    __syncthreads();

    for (int t = 0; t < TT; ++t) {
        bf16x8 xf[4];
#pragma unroll
        for (int m = 0; m < 4; ++m) {
            BF8U u;
            if (g < 2) {
                const float* xp = x + ((size_t)nodeg[m] * TT + t) * FI + g * 8;
                float4 v0 = *(const float4*)xp;
                float4 v1 = *(const float4*)(xp + 4);
                u.s[0] = f2b(v0.x); u.s[1] = f2b(v0.y); u.s[2] = f2b(v0.z); u.s[3] = f2b(v0.w);
                u.s[4] = f2b(v1.x); u.s[5] = f2b(v1.y); u.s[6] = f2b(v1.z); u.s[7] = f2b(v1.w);
            } else {
#pragma unroll
                for (int e = 0; e < 8; ++e) u.s[e] = 0;
            }
            xf[m] = u.v;
        }

        f32x4 acc[3][4], acci[4];
#pragma unroll
        for (int a = 0; a < 3; ++a)
#pragma unroll
            for (int m = 0; m < 4; ++m) acc[a][m] = (f32x4){0.f, 0.f, 0.f, 0.f};
#pragma unroll
        for (int m = 0; m < 4; ++m) acci[m] = (f32x4){0.f, 0.f, 0.f, 0.f};

#pragma unroll
        for (int s = 0; s < 4; ++s) {
            bf16x8 bf[4];
#pragma unroll
            for (int m = 0; m < 4; ++m)
                bf[m] = *(const bf16x8*)&hb[m * 16 + l15][s * 32 + g * 8];
#pragma unroll
            for (int a = 0; a < 3; ++a)
#pragma unroll
                for (int m = 0; m < 4; ++m)
                    acc[a][m] = __builtin_amdgcn_mfma_f32_16x16x32_bf16(Ah[a][s], bf[m], acc[a][m], 0, 0, 0);
        }
#pragma unroll
        for (int m = 0; m < 4; ++m) {
            acc[0][m] = __builtin_amdgcn_mfma_f32_16x16x32_bf16(Ai[0], xf[m], acc[0][m], 0, 0, 0);
            acc[1][m] = __builtin_amdgcn_mfma_f32_16x16x32_bf16(Ai[1], xf[m], acc[1][m], 0, 0, 0);
            acci[m]   = __builtin_amdgcn_mfma_f32_16x16x32_bf16(Ai[2], xf[m], acci[m], 0, 0, 0);
        }
        __syncthreads();

#pragma unroll
        for (int m = 0; m < 4; ++m) {
            u16 hp[4];
#pragma unroll
            for (int r = 0; r < 4; ++r) {
                float rr = fsigmoid(acc[0][m][r] + br4[r]);
                float zz = fsigmoid(acc[1][m][r] + bz4[r]);
                float nn = ftanh(acci[m][r] + bni4[r] + rr * (acc[2][m][r] + bnh4[r]));
                float h = nn + zz * (hreg[m][r] - nn);
                hreg[m][r] = h;
                hp[r] = f2b(h);
            }
            u32 lo = (u32)hp[0] | ((u32)hp[1] << 16);
            u32 hi = (u32)hp[2] | ((u32)hp[3] << 16);
            *(uint2*)&hb[m * 16 + l15][j0] = make_uint2(lo, hi);
        }
        __syncthreads();
    }

#pragma unroll
    for (int m = 0; m < 4; ++m) {
        int nd = gbase + m * 16 + l15;
        if (nd < NND)
            *(f32x4*)(hout + (size_t)nd * HD + j0) = hreg[m];
    }
}

// ---------------- projection: Y[N][M] = X[N][128] @ WT (+bias) (+X residual) ----------------
template <int M, bool BIAS, bool RES>
__global__ __launch_bounds__(256) void proj_kernel(
    const float* __restrict__ X, const float* __restrict__ WT,
    const float* __restrict__ bias, float* __restrict__ Y, int n_total)
{
    constexpr int K = 128;
    constexpr int MG = M / 4;
    constexpr int NG = 256 / MG;
    constexpr int NN = 64 / NG;
    __shared__ float XT[K][68];

    const int tid = threadIdx.x;
    const int gbase = blockIdx.x * 64;

#pragma unroll
    for (int i = 0; i < 8; ++i) {
        int lin = tid + 256 * i;
        int n = lin >> 5;
        int k4 = (lin & 31) * 4;
        int gn = gbase + n; if (gn >= n_total) gn = n_total - 1;
        float4 v = *(const float4*)(X + (size_t)gn * K + k4);
        XT[k4 + 0][n] = v.x; XT[k4 + 1][n] = v.y;
        XT[k4 + 2][n] = v.z; XT[k4 + 3][n] = v.w;
    }
    __syncthreads();

    const int mg = tid % MG, ng = tid / MG;
    const int m0 = mg * 4, nb = ng * NN;
    float acc[NN][4];
#pragma unroll
    for (int a = 0; a < NN; ++a)
#pragma unroll
        for (int b = 0; b < 4; ++b) acc[a][b] = 0.f;

    for (int k = 0; k < K; ++k) {
        float4 wv4 = *(const float4*)(WT + k * M + m0);
        float wv[4] = {wv4.x, wv4.y, wv4.z, wv4.w};
        float xv[NN];
#pragma unroll
        for (int c = 0; c < NN; c += 4) {
            float4 xt = *(const float4*)&XT[k][nb + c];
            xv[c + 0] = xt.x; xv[c + 1] = xt.y; xv[c + 2] = xt.z; xv[c + 3] = xt.w;
        }
#pragma unroll
        for (int ni = 0; ni < NN; ++ni)
#pragma unroll
            for (int mm = 0; mm < 4; ++mm)
                acc[ni][mm] = fmaf(xv[ni], wv[mm], acc[ni][mm]);
    }

    float bv[4] = {0.f, 0.f, 0.f, 0.f};
    if (BIAS) { float4 b4 = *(const float4*)(bias + m0); bv[0]=b4.x; bv[1]=b4.y; bv[2]=b4.z; bv[3]=b4.w; }
#pragma unroll
    for (int ni = 0; ni < NN; ++ni) {
        int gn = gbase + nb + ni;
        if (gn < n_total) {
            float r0 = acc[ni][0] + bv[0], r1 = acc[ni][1] + bv[1];
            float r2 = acc[ni][2] + bv[2], r3 = acc[ni][3] + bv[3];
            if constexpr (RES) {
                float4 xr = *(const float4*)(X + (size_t)gn * K + m0);
                r0 += xr.x; r1 += xr.y; r2 += xr.z; r3 += xr.w;
            }
            *(float4*)(Y + (size_t)gn * M + m0) = make_float4(r0, r1, r2, r3);
        }
    }
}

// ---------------- CSR construction ----------------
__global__ void count_kernel(const int* __restrict__ dst, int* __restrict__ cnt) {
    int e = blockIdx.x * 256 + threadIdx.x;
    if (e < NE) atomicAdd(&cnt[dst[e]], 1);
}

// per-1024-chunk sums
__global__ void blocksum_kernel(const int* __restrict__ cnt, int* __restrict__ bsum) {
    __shared__ int sh[256];
    int b = blockIdx.x, t = threadIdx.x;
    int base = b * 1024;
    int s = 0;
    for (int i = t; i < 1024; i += 256) {
        int idx = base + i;
        s += (idx < NND) ? cnt[idx] : 0;
    }
    sh[t] = s; __syncthreads();
    for (int o = 128; o > 0; o >>= 1) { if (t < o) sh[t] += sh[t + o]; __syncthreads(); }
    if (t == 0) bsum[b] = sh[0];
}

__global__ void scanbsum_kernel(int* __restrict__ bsum, int nb, int* __restrict__ rowptr) {
    if (threadIdx.x == 0 && blockIdx.x == 0) {
        int acc = 0;
        for (int i = 0; i < nb; ++i) { int v = bsum[i]; bsum[i] = acc; acc += v; }
        rowptr[NND] = NE;
    }
}

__global__ void scan_kernel(const int* __restrict__ cnt, const int* __restrict__ bsum,
                            int* __restrict__ rowptr) {
    __shared__ int sh[256];
    int b = blockIdx.x, t = threadIdx.x;
    int base = b * 1024;
    int v[4], loc = 0;
#pragma unroll
    for (int j = 0; j < 4; ++j) {
        int idx = base + t * 4 + j;
        v[j] = (idx < NND) ? cnt[idx] : 0;
        loc += v[j];
    }
    sh[t] = loc; __syncthreads();
    for (int o = 1; o < 256; o <<= 1) {
        int x = (t >= o) ? sh[t - o] : 0;
        __syncthreads();
        sh[t] += x;
        __syncthreads();
    }
    int acc = bsum[b] + sh[t] - loc;   // exclusive base for this thread
#pragma unroll
    for (int j = 0; j < 4; ++j) {
        int idx = base + t * 4 + j;
        if (idx < NND) rowptr[idx] = acc;
        acc += v[j];
    }
}

__global__ void fill_kernel(const int* __restrict__ src, const int* __restrict__ dst,
                            const int* __restrict__ rowptr, int* __restrict__ fill,
                            int* __restrict__ csr) {
    int e = blockIdx.x * 256 + threadIdx.x;
    if (e >= NE) return;
    int d = dst[e];
    int pos = rowptr[d] + atomicAdd(&fill[d], 1);
    csr[pos] = src[e];
}

// ---------------- gather-aggregate (mean) + combine, one wave per node ----------------
// F=128: lane holds float2; F=64: lane holds float1.
template <int F, bool RELU>
__global__ __launch_bounds__(256) void gather_kernel(
    const float* __restrict__ P,     // [N][F] projected features
    const int* __restrict__ rowptr, const int* __restrict__ csr,
    const float* __restrict__ q,     // [N][F] self-path (bias/residual folded)
    float* __restrict__ outp)        // [N][F]
{
    int n = ((blockIdx.x * 256 + threadIdx.x) >> 6);
    if (n >= NND) return;
    int lane = threadIdx.x & 63;
    int beg = rowptr[n], end = rowptr[n + 1];

    if constexpr (F == 128) {
        float2 acc = make_float2(0.f, 0.f);
        for (int cb = beg; cb < end; cb += 64) {
            int myi = (cb + lane < end) ? csr[cb + lane] : 0;
            int nn = min(end - cb, 64);
            for (int i = 0; i < nn; ++i) {
                int s = __shfl(myi, i);
                float2 v = *(const float2*)(P + (size_t)s * F + lane * 2);
                acc.x += v.x; acc.y += v.y;
            }
        }
        int deg = end - beg;
        float inv = 1.0f / (float)(deg > 0 ? deg : 1);
        float2 qv = *(const float2*)(q + (size_t)n * F + lane * 2);
        float r0 = acc.x * inv + qv.x, r1 = acc.y * inv + qv.y;
        if (RELU) { r0 = fmaxf(r0, 0.f); r1 = fmaxf(r1, 0.f); }
        *(float2*)(outp + (size_t)n * F + lane * 2) = make_float2(r0, r1);
    } else {
        float acc = 0.f;
        for (int cb = beg; cb < end; cb += 64) {
            int myi = (cb + lane < end) ? csr[cb + lane] : 0;
            int nn = min(end - cb, 64);
            for (int i = 0; i < nn; ++i) {
                int s = __shfl(myi, i);
                acc += P[(size_t)s * F + lane];
            }
        }
        int deg = end - beg;
        float inv = 1.0f / (float)(deg > 0 ? deg : 1);
        float r = acc * inv + q[(size_t)n * F + lane];
        if (RELU) r = fmaxf(r, 0.f);
        outp[(size_t)n * F + lane] = r;
    }
}

// ---------------- launch ----------------
extern "C" void kernel_launch(void* const* d_in, const int* in_sizes, int n_in,
                              void* d_out, int out_size, void* d_ws, size_t ws_size,
                              hipStream_t stream) {
    const float* x   = (const float*)d_in[0];
    const int*   edg = (const int*)d_in[1];
    const int*   src = edg;
    const int*   dst = edg + NE;
    const float* Wih = (const float*)d_in[2];
    const float* Whh = (const float*)d_in[3];
    const float* bih = (const float*)d_in[4];
    const float* bhh = (const float*)d_in[5];
    const float* W1l = (const float*)d_in[6];
    const float* b1  = (const float*)d_in[7];
    const float* W1r = (const float*)d_in[8];
    const float* W2l = (const float*)d_in[9];
    const float* b2  = (const float*)d_in[10];
    const float* W2r = (const float*)d_in[11];
    float* out = (float*)d_out;

    char* wsp = (char*)d_ws;
    auto alloc = [&](size_t nbytes) {
        char* p = wsp; wsp += (nbytes + 255) & ~(size_t)255; return p;
    };
    u16*   Ap    = (u16*)alloc((size_t)6144 * 8 * 2);
    u16*   Aip   = (u16*)alloc((size_t)1536 * 8 * 2);
    float* WT1l  = (float*)alloc((size_t)HD * HD * 4);
    float* WT1r  = (float*)alloc((size_t)HD * HD * 4);
    float* WT2l  = (float*)alloc((size_t)HD * OD * 4);
    float* WT2r  = (float*)alloc((size_t)HD * OD * 4);
    int*   cnt   = (int*)alloc((size_t)NND * 4);
    int*   fill  = (int*)alloc((size_t)NND * 4);
    int*   rowp  = (int*)alloc((size_t)(NND + 1) * 4);
    int*   bsum  = (int*)alloc((size_t)128 * 4);
    int*   csr   = (int*)alloc((size_t)NE * 4);
    float* h     = (float*)alloc((size_t)NND * HD * 4);
    float* p     = (float*)alloc((size_t)NND * HD * 4);
    float* q     = (float*)alloc((size_t)NND * HD * 4);
    float* g     = (float*)alloc((size_t)NND * HD * 4);

    const int NB_SCAN = (NND + 1023) / 1024;   // 98

    hipMemsetAsync(cnt, 0, (size_t)NND * 4, stream);
    hipMemsetAsync(fill, 0, (size_t)NND * 4, stream);

    // prep
    pack_w_kernel<<<30, 256, 0, stream>>>(Whh, Wih, Ap, Aip);
    transpose_kernel<<<(HD * HD + 255) / 256, 256, 0, stream>>>(W1l, WT1l, HD, HD);
    transpose_kernel<<<(HD * HD + 255) / 256, 256, 0, stream>>>(W1r, WT1r, HD, HD);
    transpose_kernel<<<(OD * HD + 255) / 256, 256, 0, stream>>>(W2l, WT2l, OD, HD);
    transpose_kernel<<<(OD * HD + 255) / 256, 256, 0, stream>>>(W2r, WT2r, OD, HD);

    // CSR build (overlaps GRU on the same stream queue; independent of h)
    count_kernel<<<(NE + 255) / 256, 256, 0, stream>>>(dst, cnt);
    blocksum_kernel<<<NB_SCAN, 256, 0, stream>>>(cnt, bsum);
    scanbsum_kernel<<<1, 64, 0, stream>>>(bsum, NB_SCAN, rowp);
    scan_kernel<<<NB_SCAN, 256, 0, stream>>>(cnt, bsum, rowp);
    fill_kernel<<<(NE + 255) / 256, 256, 0, stream>>>(src, dst, rowp, fill, csr);

    // GRU -> h [N,128]
    const int nblk = (NND + 63) / 64;
    gru_mfma_kernel<<<nblk, 512, 0, stream>>>(x, Ap, Aip, bih, bhh, h);

    // layer 1: project, then mean-gather (+q, relu) fused
    proj_kernel<HD, false, false><<<nblk, 256, 0, stream>>>(h, WT1l, nullptr, p, NND);
    proj_kernel<HD, true,  true ><<<nblk, 256, 0, stream>>>(h, WT1r, b1, q, NND);  // q = h@W1r^T + b1 + h
    gather_kernel<HD, true><<<(NND * 64 + 255) / 256, 256, 0, stream>>>(p, rowp, csr, q, g);

    // layer 2: project to 64, then mean-gather (+q)
    proj_kernel<OD, false, false><<<nblk, 256, 0, stream>>>(g, WT2l, nullptr, p, NND);
    proj_kernel<OD, true,  false><<<nblk, 256, 0, stream>>>(g, WT2r, b2, q, NND);
    gather_kernel<OD, false><<<(NND * 64 + 255) / 256, 256, 0, stream>>>(p, rowp, csr, q, out);
}

// Round 4
// 1101.126 us; speedup vs baseline: 8.8078x; 1.1711x over previous
//
#include <hip/hip_runtime.h>
#include <math.h>

#define NND 100000
#define TT 24
#define FI 16
#define HD 128
#define GD 384   // 3*HD
#define OD 64
#define NE 1600000

typedef __bf16 bf16x8 __attribute__((ext_vector_type(8)));
typedef float f32x4 __attribute__((ext_vector_type(4)));
typedef unsigned short u16;
typedef unsigned int u32;

__device__ __forceinline__ float fsigmoid(float v) {
    return __builtin_amdgcn_rcpf(1.0f + __expf(-v));
}
__device__ __forceinline__ float ftanh(float v) {
    return 1.0f - 2.0f * __builtin_amdgcn_rcpf(1.0f + __expf(2.0f * v));
}
__device__ __forceinline__ u16 f2b(float f) {
    u32 u = __float_as_uint(f);
    u32 r = (u + 0x7FFFu + ((u >> 16) & 1u)) >> 16;
    return (u16)r;
}
__device__ __forceinline__ u32 cvtpk(float lo, float hi) {
    u32 r;
    asm("v_cvt_pk_bf16_f32 %0, %1, %2" : "=v"(r) : "v"(lo), "v"(hi));
    return r;
}

union BF8U { u16 s[8]; bf16x8 v; };

// ---------------- transpose W[rows][cols] -> WT[cols][rows] ----------------
__global__ void transpose_kernel(const float* __restrict__ W, float* __restrict__ WT,
                                 int rows, int cols) {
    int idx = blockIdx.x * 256 + threadIdx.x;
    if (idx < rows * cols) {
        int r = idx / cols, c = idx % cols;
        WT[c * rows + r] = W[idx];
    }
}

// ---------------- x f32 -> bf16 (once) ----------------
__global__ void cvt_x_kernel(const float* __restrict__ x, u16* __restrict__ xb) {
    size_t base = ((size_t)blockIdx.x * 256 + threadIdx.x) * 8;
    float4 a = *(const float4*)(x + base);
    float4 b = *(const float4*)(x + base + 4);
    u32 o0 = cvtpk(a.x, a.y), o1 = cvtpk(a.z, a.w);
    u32 o2 = cvtpk(b.x, b.y), o3 = cvtpk(b.z, b.w);
    *(uint4*)(xb + base) = make_uint4(o0, o1, o2, o3);
}

// ---------------- pack GRU weights into MFMA A-fragments (bf16) ----------------
__global__ void pack_w_kernel(const float* __restrict__ Whh, const float* __restrict__ Wih,
                              u16* __restrict__ Ap, u16* __restrict__ Aip) {
    int id = blockIdx.x * 256 + threadIdx.x;
    if (id < 6144) {
        int lane = id & 63, fs = id >> 6;
        int s = fs & 3, gt = fs >> 2;
        int row = gt * 16 + (lane & 15);
        int k0 = s * 32 + (lane >> 4) * 8;
        const float* src = Whh + (size_t)row * HD + k0;
        u16 o[8];
#pragma unroll
        for (int e = 0; e < 8; ++e) o[e] = f2b(src[e]);
        u32* dst = (u32*)(Ap + (size_t)id * 8);
#pragma unroll
        for (int e = 0; e < 4; ++e) dst[e] = (u32)o[2 * e] | ((u32)o[2 * e + 1] << 16);
    } else if (id < 7680) {
        int id2 = id - 6144;
        int lane = id2 & 63, gt = id2 >> 6;
        int row = gt * 16 + (lane & 15);
        int k0 = (lane >> 4) * 8;
        u16 o[8] = {0, 0, 0, 0, 0, 0, 0, 0};
        if (k0 < FI) {
            const float* src = Wih + (size_t)row * FI + k0;
#pragma unroll
            for (int e = 0; e < 8; ++e) o[e] = f2b(src[e]);
        }
        u32* dst = (u32*)(Aip + (size_t)id2 * 8);
#pragma unroll
        for (int e = 0; e < 4; ++e) dst[e] = (u32)o[2 * e] | ((u32)o[2 * e + 1] << 16);
    }
}

// swizzled LDS index (u16 units): row stride 128, XOR bank swizzle
__device__ __forceinline__ int hidx(int row, int col) {
    return row * 128 + (col ^ ((row & 7) << 3));
}

// ---------------- GRU via MFMA: 64 nodes / 512-thread block ----------------
// Double-buffered swizzled h LDS, 1 barrier/step, m-split phases.
__global__ __launch_bounds__(512) void gru_mfma_kernel(
    const u16* __restrict__ xb,       // [N][T][16] bf16
    const u16* __restrict__ Ap,       // [24][4][64][8] bf16 (Whh frags)
    const u16* __restrict__ Aip,      // [24][64][8] bf16 (Wih frags)
    const float* __restrict__ bih, const float* __restrict__ bhh,
    float* __restrict__ hout)         // [N][128] f32
{
    __shared__ u16 hb[2][64 * 128];

    const int tid = threadIdx.x;
    const int w = tid >> 6, lane = tid & 63;
    const int l15 = lane & 15, g = lane >> 4;
    const int gbase = blockIdx.x * 64;
    const int j0 = w * 16 + g * 4;

    for (int i = tid; i < 64 * 128 / 2; i += 512) ((u32*)hb[0])[i] = 0u;

    bf16x8 Ah[3][4], Ai[3];
#pragma unroll
    for (int a = 0; a < 3; ++a) {
        int gt = w + a * 8;
#pragma unroll
        for (int s = 0; s < 4; ++s)
            Ah[a][s] = *(const bf16x8*)(Ap + ((size_t)(gt * 4 + s) * 64 + lane) * 8);
        Ai[a] = *(const bf16x8*)(Aip + ((size_t)gt * 64 + lane) * 8);
    }

    f32x4 br4, bz4, bnh4, bni4;
    {
        f32x4 a0 = *(const f32x4*)(bih + j0),        b0 = *(const f32x4*)(bhh + j0);
        f32x4 a1 = *(const f32x4*)(bih + 128 + j0),  b1 = *(const f32x4*)(bhh + 128 + j0);
        br4 = a0 + b0; bz4 = a1 + b1;
        bnh4 = *(const f32x4*)(bhh + 256 + j0);
        bni4 = *(const f32x4*)(bih + 256 + j0);
    }

    const f32x4 fz = {0.f, 0.f, 0.f, 0.f};
    bf16x8 xz;
    *(uint4*)&xz = make_uint4(0u, 0u, 0u, 0u);

    f32x4 hreg[4];
#pragma unroll
    for (int m = 0; m < 4; ++m) hreg[m] = fz;

    int nodeg[4];
#pragma unroll
    for (int m = 0; m < 4; ++m) {
        int nd = gbase + m * 16 + l15;
        nodeg[m] = nd < NND ? nd : NND - 1;
    }

    __syncthreads();

#pragma unroll 1
    for (int t = 0; t < TT; ++t) {
        const u16* rb = hb[t & 1];
        u16* wbuf = hb[(t & 1) ^ 1];

        // x B-fragments: one 16B load (g<2 lanes), zeros elsewhere
        bf16x8 xf[4];
#pragma unroll
        for (int m = 0; m < 4; ++m)
            xf[m] = (g < 2)
                  ? *(const bf16x8*)(xb + ((size_t)nodeg[m] * TT + t) * FI + g * 8)
                  : xz;

#pragma unroll
        for (int mh = 0; mh < 2; ++mh) {
            const int ra = (mh * 2) * 16 + l15;
            const int rbr = (mh * 2 + 1) * 16 + l15;
            f32x4 acc[3][2], acci[2];

            // s = 0 seeds accumulators from persistent zero (no per-step movs)
            {
                bf16x8 b0 = *(const bf16x8*)&rb[hidx(ra, g * 8)];
                bf16x8 b1 = *(const bf16x8*)&rb[hidx(rbr, g * 8)];
#pragma unroll
                for (int a = 0; a < 3; ++a) {
                    acc[a][0] = __builtin_amdgcn_mfma_f32_16x16x32_bf16(Ah[a][0], b0, fz, 0, 0, 0);
                    acc[a][1] = __builtin_amdgcn_mfma_f32_16x16x32_bf16(Ah[a][0], b1, fz, 0, 0, 0);
                }
            }
#pragma unroll
            for (int s = 1; s < 4; ++s) {
                bf16x8 b0 = *(const bf16x8*)&rb[hidx(ra, s * 32 + g * 8)];
                bf16x8 b1 = *(const bf16x8*)&rb[hidx(rbr, s * 32 + g * 8)];
#pragma unroll
                for (int a = 0; a < 3; ++a) {
                    acc[a][0] = __builtin_amdgcn_mfma_f32_16x16x32_bf16(Ah[a][s], b0, acc[a][0], 0, 0, 0);
                    acc[a][1] = __builtin_amdgcn_mfma_f32_16x16x32_bf16(Ah[a][s], b1, acc[a][1], 0, 0, 0);
                }
            }
            // input projection
#pragma unroll
            for (int mi = 0; mi < 2; ++mi) {
                bf16x8 xv = xf[mh * 2 + mi];
                acc[0][mi] = __builtin_amdgcn_mfma_f32_16x16x32_bf16(Ai[0], xv, acc[0][mi], 0, 0, 0);
                acc[1][mi] = __builtin_amdgcn_mfma_f32_16x16x32_bf16(Ai[1], xv, acc[1][mi], 0, 0, 0);
                acci[mi]   = __builtin_amdgcn_mfma_f32_16x16x32_bf16(Ai[2], xv, fz, 0, 0, 0);
            }

            // gates (register-local) + packed bf16 write to the OTHER buffer
#pragma unroll
            for (int mi = 0; mi < 2; ++mi) {
                int m = mh * 2 + mi;
#pragma unroll
                for (int r = 0; r < 4; ++r) {
                    float rr = fsigmoid(acc[0][mi][r] + br4[r]);
                    float zz = fsigmoid(acc[1][mi][r] + bz4[r]);
                    float nn = ftanh(acci[mi][r] + bni4[r] + rr * (acc[2][mi][r] + bnh4[r]));
                    float h = nn + zz * (hreg[m][r] - nn);
                    hreg[m][r] = h;
                }
                u32 p0 = cvtpk(hreg[m][0], hreg[m][1]);
                u32 p1 = cvtpk(hreg[m][2], hreg[m][3]);
                *(uint2*)&wbuf[hidx(m * 16 + l15, j0)] = make_uint2(p0, p1);
            }
        }
        __syncthreads();   // single barrier per step (double-buffered)
    }

#pragma unroll
    for (int m = 0; m < 4; ++m) {
        int nd = gbase + m * 16 + l15;
        if (nd < NND)
            *(f32x4*)(hout + (size_t)nd * HD + j0) = hreg[m];
    }
}

// ---------------- projection: Y[N][M] = X[N][128] @ WT (+bias) (+X residual) ----------------
template <int M, bool BIAS, bool RES>
__global__ __launch_bounds__(256) void proj_kernel(
    const float* __restrict__ X, const float* __restrict__ WT,
    const float* __restrict__ bias, float* __restrict__ Y, int n_total)
{
    constexpr int K = 128;
    constexpr int MG = M / 4;
    constexpr int NG = 256 / MG;
    constexpr int NN = 64 / NG;
    __shared__ float XT[K][68];

    const int tid = threadIdx.x;
    const int gbase = blockIdx.x * 64;

#pragma unroll
    for (int i = 0; i < 8; ++i) {
        int lin = tid + 256 * i;
        int n = lin >> 5;
        int k4 = (lin & 31) * 4;
        int gn = gbase + n; if (gn >= n_total) gn = n_total - 1;
        float4 v = *(const float4*)(X + (size_t)gn * K + k4);
        XT[k4 + 0][n] = v.x; XT[k4 + 1][n] = v.y;
        XT[k4 + 2][n] = v.z; XT[k4 + 3][n] = v.w;
    }
    __syncthreads();

    const int mg = tid % MG, ng = tid / MG;
    const int m0 = mg * 4, nb = ng * NN;
    float acc[NN][4];
#pragma unroll
    for (int a = 0; a < NN; ++a)
#pragma unroll
        for (int b = 0; b < 4; ++b) acc[a][b] = 0.f;

    for (int k = 0; k < K; ++k) {
        float4 wv4 = *(const float4*)(WT + k * M + m0);
        float wv[4] = {wv4.x, wv4.y, wv4.z, wv4.w};
        float xv[NN];
#pragma unroll
        for (int c = 0; c < NN; c += 4) {
            float4 xt = *(const float4*)&XT[k][nb + c];
            xv[c + 0] = xt.x; xv[c + 1] = xt.y; xv[c + 2] = xt.z; xv[c + 3] = xt.w;
        }
#pragma unroll
        for (int ni = 0; ni < NN; ++ni)
#pragma unroll
            for (int mm = 0; mm < 4; ++mm)
                acc[ni][mm] = fmaf(xv[ni], wv[mm], acc[ni][mm]);
    }

    float bv[4] = {0.f, 0.f, 0.f, 0.f};
    if (BIAS) { float4 b4 = *(const float4*)(bias + m0); bv[0]=b4.x; bv[1]=b4.y; bv[2]=b4.z; bv[3]=b4.w; }
#pragma unroll
    for (int ni = 0; ni < NN; ++ni) {
        int gn = gbase + nb + ni;
        if (gn < n_total) {
            float r0 = acc[ni][0] + bv[0], r1 = acc[ni][1] + bv[1];
            float r2 = acc[ni][2] + bv[2], r3 = acc[ni][3] + bv[3];
            if constexpr (RES) {
                float4 xr = *(const float4*)(X + (size_t)gn * K + m0);
                r0 += xr.x; r1 += xr.y; r2 += xr.z; r3 += xr.w;
            }
            *(float4*)(Y + (size_t)gn * M + m0) = make_float4(r0, r1, r2, r3);
        }
    }
}

// ---------------- CSR construction ----------------
__global__ void count_kernel(const int* __restrict__ dst, int* __restrict__ cnt) {
    int e = blockIdx.x * 256 + threadIdx.x;
    if (e < NE) atomicAdd(&cnt[dst[e]], 1);
}

__global__ void blocksum_kernel(const int* __restrict__ cnt, int* __restrict__ bsum) {
    __shared__ int sh[256];
    int b = blockIdx.x, t = threadIdx.x;
    int base = b * 1024;
    int s = 0;
    for (int i = t; i < 1024; i += 256) {
        int idx = base + i;
        s += (idx < NND) ? cnt[idx] : 0;
    }
    sh[t] = s; __syncthreads();
    for (int o = 128; o > 0; o >>= 1) { if (t < o) sh[t] += sh[t + o]; __syncthreads(); }
    if (t == 0) bsum[b] = sh[0];
}

__global__ void scanbsum_kernel(int* __restrict__ bsum, int nb, int* __restrict__ rowptr) {
    if (threadIdx.x == 0 && blockIdx.x == 0) {
        int acc = 0;
        for (int i = 0; i < nb; ++i) { int v = bsum[i]; bsum[i] = acc; acc += v; }
        rowptr[NND] = NE;
    }
}

__global__ void scan_kernel(const int* __restrict__ cnt, const int* __restrict__ bsum,
                            int* __restrict__ rowptr) {
    __shared__ int sh[256];
    int b = blockIdx.x, t = threadIdx.x;
    int base = b * 1024;
    int v[4], loc = 0;
#pragma unroll
    for (int j = 0; j < 4; ++j) {
        int idx = base + t * 4 + j;
        v[j] = (idx < NND) ? cnt[idx] : 0;
        loc += v[j];
    }
    sh[t] = loc; __syncthreads();
    for (int o = 1; o < 256; o <<= 1) {
        int x = (t >= o) ? sh[t - o] : 0;
        __syncthreads();
        sh[t] += x;
        __syncthreads();
    }
    int acc = bsum[b] + sh[t] - loc;
#pragma unroll
    for (int j = 0; j < 4; ++j) {
        int idx = base + t * 4 + j;
        if (idx < NND) rowptr[idx] = acc;
        acc += v[j];
    }
}

__global__ void fill_kernel(const int* __restrict__ src, const int* __restrict__ dst,
                            const int* __restrict__ rowptr, int* __restrict__ fill,
                            int* __restrict__ csr) {
    int e = blockIdx.x * 256 + threadIdx.x;
    if (e >= NE) return;
    int d = dst[e];
    int pos = rowptr[d] + atomicAdd(&fill[d], 1);
    csr[pos] = src[e];
}

// ---------------- gather-aggregate (mean) + combine, one wave per node ----------------
template <int F, bool RELU>
__global__ __launch_bounds__(256) void gather_kernel(
    const float* __restrict__ P,
    const int* __restrict__ rowptr, const int* __restrict__ csr,
    const float* __restrict__ q,
    float* __restrict__ outp)
{
    int n = ((blockIdx.x * 256 + threadIdx.x) >> 6);
    if (n >= NND) return;
    int lane = threadIdx.x & 63;
    int beg = rowptr[n], end = rowptr[n + 1];

    if constexpr (F == 128) {
        float2 acc = make_float2(0.f, 0.f);
        for (int cb = beg; cb < end; cb += 64) {
            int myi = (cb + lane < end) ? csr[cb + lane] : 0;
            int nn = min(end - cb, 64);
            for (int i = 0; i < nn; ++i) {
                int s = __shfl(myi, i);
                float2 v = *(const float2*)(P + (size_t)s * F + lane * 2);
                acc.x += v.x; acc.y += v.y;
            }
        }
        int deg = end - beg;
        float inv = 1.0f / (float)(deg > 0 ? deg : 1);
        float2 qv = *(const float2*)(q + (size_t)n * F + lane * 2);
        float r0 = acc.x * inv + qv.x, r1 = acc.y * inv + qv.y;
        if (RELU) { r0 = fmaxf(r0, 0.f); r1 = fmaxf(r1, 0.f); }
        *(float2*)(outp + (size_t)n * F + lane * 2) = make_float2(r0, r1);
    } else {
        float acc = 0.f;
        for (int cb = beg; cb < end; cb += 64) {
            int myi = (cb + lane < end) ? csr[cb + lane] : 0;
            int nn = min(end - cb, 64);
            for (int i = 0; i < nn; ++i) {
                int s = __shfl(myi, i);
                acc += P[(size_t)s * F + lane];
            }
        }
        int deg = end - beg;
        float inv = 1.0f / (float)(deg > 0 ? deg : 1);
        float r = acc * inv + q[(size_t)n * F + lane];
        if (RELU) r = fmaxf(r, 0.f);
        outp[(size_t)n * F + lane] = r;
    }
}

// ---------------- launch ----------------
extern "C" void kernel_launch(void* const* d_in, const int* in_sizes, int n_in,
                              void* d_out, int out_size, void* d_ws, size_t ws_size,
                              hipStream_t stream) {
    const float* x   = (const float*)d_in[0];
    const int*   edg = (const int*)d_in[1];
    const int*   src = edg;
    const int*   dst = edg + NE;
    const float* Wih = (const float*)d_in[2];
    const float* Whh = (const float*)d_in[3];
    const float* bih = (const float*)d_in[4];
    const float* bhh = (const float*)d_in[5];
    const float* W1l = (const float*)d_in[6];
    const float* b1  = (const float*)d_in[7];
    const float* W1r = (const float*)d_in[8];
    const float* W2l = (const float*)d_in[9];
    const float* b2  = (const float*)d_in[10];
    const float* W2r = (const float*)d_in[11];
    float* out = (float*)d_out;

    char* wsp = (char*)d_ws;
    auto alloc = [&](size_t nbytes) {
        char* p = wsp; wsp += (nbytes + 255) & ~(size_t)255; return p;
    };
    u16*   Ap    = (u16*)alloc((size_t)6144 * 8 * 2);
    u16*   Aip   = (u16*)alloc((size_t)1536 * 8 * 2);
    float* WT1l  = (float*)alloc((size_t)HD * HD * 4);
    float* WT1r  = (float*)alloc((size_t)HD * HD * 4);
    float* WT2l  = (float*)alloc((size_t)HD * OD * 4);
    float* WT2r  = (float*)alloc((size_t)HD * OD * 4);
    int*   cnt   = (int*)alloc((size_t)NND * 4);
    int*   fill  = (int*)alloc((size_t)NND * 4);
    int*   rowp  = (int*)alloc((size_t)(NND + 1) * 4);
    int*   bsum  = (int*)alloc((size_t)128 * 4);
    int*   csr   = (int*)alloc((size_t)NE * 4);
    float* h     = (float*)alloc((size_t)NND * HD * 4);
    float* p     = (float*)alloc((size_t)NND * HD * 4);
    float* q     = (float*)alloc((size_t)NND * HD * 4);
    float* g     = (float*)alloc((size_t)NND * HD * 4);
    // xb ([N][T][16] bf16 = 76.8 MB) aliases q+g (102.4 MB): xb is consumed by
    // the GRU before q or g are first written (same stream -> ordered).
    u16*   xb    = (u16*)q;

    const int NB_SCAN = (NND + 1023) / 1024;

    hipMemsetAsync(cnt, 0, (size_t)NND * 4, stream);
    hipMemsetAsync(fill, 0, (size_t)NND * 4, stream);

    // prep
    cvt_x_kernel<<<(NND * TT * FI) / (256 * 8), 256, 0, stream>>>(x, xb);
    pack_w_kernel<<<30, 256, 0, stream>>>(Whh, Wih, Ap, Aip);
    transpose_kernel<<<(HD * HD + 255) / 256, 256, 0, stream>>>(W1l, WT1l, HD, HD);
    transpose_kernel<<<(HD * HD + 255) / 256, 256, 0, stream>>>(W1r, WT1r, HD, HD);
    transpose_kernel<<<(OD * HD + 255) / 256, 256, 0, stream>>>(W2l, WT2l, OD, HD);
    transpose_kernel<<<(OD * HD + 255) / 256, 256, 0, stream>>>(W2r, WT2r, OD, HD);

    // CSR build
    count_kernel<<<(NE + 255) / 256, 256, 0, stream>>>(dst, cnt);
    blocksum_kernel<<<NB_SCAN, 256, 0, stream>>>(cnt, bsum);
    scanbsum_kernel<<<1, 64, 0, stream>>>(bsum, NB_SCAN, rowp);
    scan_kernel<<<NB_SCAN, 256, 0, stream>>>(cnt, bsum, rowp);
    fill_kernel<<<(NE + 255) / 256, 256, 0, stream>>>(src, dst, rowp, fill, csr);

    // GRU -> h [N,128]
    const int nblk = (NND + 63) / 64;
    gru_mfma_kernel<<<nblk, 512, 0, stream>>>(xb, Ap, Aip, bih, bhh, h);

    // layer 1: project, then mean-gather (+q, relu) fused
    proj_kernel<HD, false, false><<<nblk, 256, 0, stream>>>(h, WT1l, nullptr, p, NND);
    proj_kernel<HD, true,  true ><<<nblk, 256, 0, stream>>>(h, WT1r, b1, q, NND);
    gather_kernel<HD, true><<<(NND * 64 + 255) / 256, 256, 0, stream>>>(p, rowp, csr, q, g);

    // layer 2: project to 64, then mean-gather (+q)
    proj_kernel<OD, false, false><<<nblk, 256, 0, stream>>>(g, WT2l, nullptr, p, NND);
    proj_kernel<OD, true,  false><<<nblk, 256, 0, stream>>>(g, WT2r, b2, q, NND);
    gather_kernel<OD, false><<<(NND * 64 + 255) / 256, 256, 0, stream>>>(p, rowp, csr, q, out);
}